// Round 3
// baseline (265.822 us; speedup 1.0000x reference)
//
#include <hip/hip_runtime.h>

// ConvTranspose3d(3->16, k=3, s=2, p=1) + per-channel norm + 2x avgpool2 fused.
// y (32,16,63,63,63) never materialized. out = 4^3-pooled normalized y -> (32,16,15,15,15).
// R3: one-y-at-a-time (minimal liveness, no spills), 8 co per thread via a
// runtime loop; x patch (81 regs) loaded once per thread; weights in SGPRs.
// Index-clamp garbage flows only into lo==3 elements, which the edge masks
// (constant-folded multiplies) zero out of the stats; pool writes interior only.

#define N_BATCH 32
#define C_OUT 16
#define P_OUT 15
#define POOL3 (P_OUT * P_OUT * P_OUT)                 // 3375
#define COUNT_Y 8001504.0f                            // 32 * 63^3
#define TOTAL_OUT (N_BATCH * C_OUT * POOL3)           // 1,728,000

// tap tables: local output offset lo -> (k, i_local) pairs   (lo = 2*il + k - 1)
// lo=0: (1,0)   lo=1: (2,0),(0,1)   lo=2: (1,1)   lo=3: (2,1),(0,2)
constexpr int NPAIR[4]  = {1, 2, 1, 2};
constexpr int PK[4][2]  = {{1, 1}, {2, 0}, {1, 1}, {2, 0}};
constexpr int PI[4][2]  = {{0, 0}, {0, 1}, {1, 1}, {1, 2}};

__global__ __launch_bounds__(256, 4) void convt_pool_stats(
    const float* __restrict__ x,        // [32][3][32][32][32]
    const float* __restrict__ w,        // [3][16][3][3][3]
    float* __restrict__ pool,           // d_out: [32][16][15][15][15] raw 4^3 sums
    float* __restrict__ partials)       // ws: sums [8192], sumsq [8192], layout [co][n][bd]
{
    const int bd  = blockIdx.x;         // 0..15
    const int cop = blockIdx.y;         // 0..1 -> co = 8*cop + c8
    const int n   = blockIdx.z;         // 0..31
    const int tid = threadIdx.x;
    const int bh = tid >> 4;            // 0..15
    const int bw = tid & 15;            // 0..15

    const int id0 = 2 * bd, ih0 = 2 * bh, iw0 = 2 * bw;
    const int idc[3] = {id0, id0 + 1, min(id0 + 2, 31)};
    const int ihc[3] = {ih0, ih0 + 1, min(ih0 + 2, 31)};
    const int iw2    = min(iw0 + 2, 31);

    // ---- x patch: 3 ci x 3x3x3, loaded once (81 VGPRs), unconditional clamped loads
    float xl[3][3][3][3];               // [ci][d][h][w]
    const float* xn = x + (size_t)n * (3 * 32768);
    #pragma unroll
    for (int ci = 0; ci < 3; ++ci) {
        const float* xc = xn + ci * 32768;
        #pragma unroll
        for (int dd = 0; dd < 3; ++dd) {
            #pragma unroll
            for (int hh = 0; hh < 3; ++hh) {
                const int ro = (idc[dd] * 32 + ihc[hh]) * 32;
                const float2 f2 = *reinterpret_cast<const float2*>(xc + ro + iw0);
                xl[ci][dd][hh][0] = f2.x;
                xl[ci][dd][hh][1] = f2.y;
                xl[ci][dd][hh][2] = xc[ro + iw2];
            }
        }
    }

    // ---- edge masks (constant-fold to 1.0 for the 27 interior elements)
    const float fd = (bd == 15) ? 0.0f : 1.0f;
    const float fh = (bh == 15) ? 0.0f : 1.0f;
    const float fw_ = (bw == 15) ? 0.0f : 1.0f;
    const float mD[4] = {1.0f, 1.0f, 1.0f, fd};
    const float mH[4] = {1.0f, 1.0f, 1.0f, fh};
    const float mW[4] = {1.0f, 1.0f, 1.0f, fw_};
    const bool inter = (bd < 15) && (bh < 15) && (bw < 15);

    __shared__ float red[4][8][2];
    const int wave = tid >> 6, lane = tid & 63;

    const int obase = ((n * C_OUT + cop * 8) * P_OUT + bd) * P_OUT * P_OUT + bh * P_OUT + bw;

    #pragma unroll 1
    for (int c8 = 0; c8 < 8; ++c8) {
        const int co = cop * 8 + c8;

        // weights: wave-uniform -> scalar loads into SGPRs
        float wl[3][27];
        #pragma unroll
        for (int ci = 0; ci < 3; ++ci) {
            const float* wp = w + ((size_t)(ci * C_OUT + co)) * 27;
            #pragma unroll
            for (int k = 0; k < 27; ++k) wl[ci][k] = wp[k];
        }

        float s0 = 0.0f, s1 = 0.0f, q0 = 0.0f, q1 = 0.0f;
        #pragma unroll
        for (int od = 0; od < 4; ++od) {
            #pragma unroll
            for (int oh = 0; oh < 4; ++oh) {
                #pragma unroll
                for (int ow = 0; ow < 4; ++ow) {
                    float y = 0.0f;
                    #pragma unroll
                    for (int ci = 0; ci < 3; ++ci) {
                        #pragma unroll
                        for (int pd = 0; pd < NPAIR[od]; ++pd) {
                            const int kd = PK[od][pd], idd = PI[od][pd];
                            #pragma unroll
                            for (int ph = 0; ph < NPAIR[oh]; ++ph) {
                                const int kh = PK[oh][ph], ihh = PI[oh][ph];
                                #pragma unroll
                                for (int pw = 0; pw < NPAIR[ow]; ++pw) {
                                    const int kw = PK[ow][pw], iww = PI[ow][pw];
                                    y = fmaf(wl[ci][kd * 9 + kh * 3 + kw],
                                             xl[ci][idd][ihh][iww], y);
                                }
                            }
                        }
                    }
                    const float m = mD[od] * mH[oh] * mW[ow];  // folds to 1.0 mostly
                    const float t = y * m;                     // folds to y when m==1.0
                    if (od & 1) { s1 += t; q1 = fmaf(t, y, q1); }
                    else        { s0 += t; q0 = fmaf(t, y, q0); }
                }
            }
        }

        float ss = s0 + s1, qq = q0 + q1;
        if (inter) pool[obase + c8 * POOL3] = ss;   // masked sum == plain sum here

        #pragma unroll
        for (int mm = 1; mm < 64; mm <<= 1) {
            ss += __shfl_xor(ss, mm, 64);
            qq += __shfl_xor(qq, mm, 64);
        }
        if (lane == 0) { red[wave][c8][0] = ss; red[wave][c8][1] = qq; }
    }

    __syncthreads();
    if (tid < 8) {
        const float ts = red[0][tid][0] + red[1][tid][0] + red[2][tid][0] + red[3][tid][0];
        const float tq = red[0][tid][1] + red[1][tid][1] + red[2][tid][1] + red[3][tid][1];
        const int co = cop * 8 + tid;
        const int p = (co * N_BATCH + n) * 16 + bd;     // [co][n][bd]
        partials[p] = ts;
        partials[8192 + p] = tq;
    }
}

__global__ __launch_bounds__(256) void finalize_stats(
    const float* __restrict__ partials,  // ws
    const float* __restrict__ gamma,
    const float* __restrict__ beta,
    float* __restrict__ ab)              // ws + 16384: a[16], b[16]
{
    const int c = blockIdx.x;            // 0..15
    const int tid = threadIdx.x;         // 256
    float s = 0.0f, q = 0.0f;
    #pragma unroll
    for (int j = tid; j < 512; j += 256) {
        s += partials[c * 512 + j];
        q += partials[8192 + c * 512 + j];
    }
    #pragma unroll
    for (int m = 1; m < 64; m <<= 1) {
        s += __shfl_xor(s, m, 64);
        q += __shfl_xor(q, m, 64);
    }
    __shared__ float red[8];
    const int wave = tid >> 6, lane = tid & 63;
    if (lane == 0) { red[wave] = s; red[4 + wave] = q; }
    __syncthreads();
    if (tid == 0) {
        const float ts = red[0] + red[1] + red[2] + red[3];
        const float tq = red[4] + red[5] + red[6] + red[7];
        const float mean = ts / COUNT_Y;
        const float var  = tq / COUNT_Y - mean * mean;
        const float invg = rsqrtf(var + 1e-5f) * gamma[c];
        ab[c]      = invg * (1.0f / 64.0f);
        ab[16 + c] = beta[c] - mean * invg;
    }
}

__global__ __launch_bounds__(256) void apply_norm(
    float* __restrict__ out, const float* __restrict__ ab)
{
    const int base = (blockIdx.x * 256 + threadIdx.x) * 4;
    if (base >= TOTAL_OUT) return;
    float4 v = *reinterpret_cast<float4*>(out + base);
    float r[4] = {v.x, v.y, v.z, v.w};
    #pragma unroll
    for (int j = 0; j < 4; ++j) {
        const int c = ((base + j) / POOL3) & 15;
        r[j] = fmaf(r[j], ab[c], ab[16 + c]);
    }
    *reinterpret_cast<float4*>(out + base) = make_float4(r[0], r[1], r[2], r[3]);
}

extern "C" void kernel_launch(void* const* d_in, const int* in_sizes, int n_in,
                              void* d_out, int out_size, void* d_ws, size_t ws_size,
                              hipStream_t stream) {
    const float* x     = (const float*)d_in[0];
    const float* w     = (const float*)d_in[1];
    const float* gamma = (const float*)d_in[2];
    const float* beta  = (const float*)d_in[3];
    float* out = (float*)d_out;
    float* ws  = (float*)d_ws;
    // ws layout (floats): [0,8192) sums, [8192,16384) sumsq, [16384,16416) a,b

    dim3 g1(16, 2, 32);   // bd, co-half, n  -> 1024 blocks
    convt_pool_stats<<<g1, 256, 0, stream>>>(x, w, out, ws);
    finalize_stats<<<16, 256, 0, stream>>>(ws, gamma, beta, ws + 16384);

    const int nv4 = TOTAL_OUT / 4;  // 432,000
    apply_norm<<<(nv4 + 255) / 256, 256, 0, stream>>>(out, ws + 16384);
}

// Round 4
// 77.698 us; speedup vs baseline: 3.4212x; 3.4212x over previous
//
#include <hip/hip_runtime.h>

// ConvTranspose3d(3->16, k=3, s=2, p=1) + per-channel norm + 2x avgpool2 fused.
// y (32,16,63,63,63) never materialized. out = 4^3-pooled normalized y -> (32,16,15,15,15).
// R4: back to R1's proven register shape (1 co/thread, 64 static accumulators,
// everything fully unrolled, NO runtime loops over live arrays) with R2's cheap
// load scheme: unconditional clamped float2 loads; clamp garbage flows only
// into y[*==3] elements, which edge threads zero before stats.

#define N_BATCH 32
#define C_OUT 16
#define P_OUT 15
#define POOL3 (P_OUT * P_OUT * P_OUT)                 // 3375
#define COUNT_Y 8001504.0f                            // 32 * 63^3
#define TOTAL_OUT (N_BATCH * C_OUT * POOL3)           // 1,728,000

// tap tables: local output offset lo -> (k, i_local) pairs
// lo=0: (1,0)   lo=1: (2,0),(0,1)   lo=2: (1,1)   lo=3: (2,1),(0,2)
constexpr int NPAIR[4]  = {1, 2, 1, 2};
constexpr int PK[4][2]  = {{1, 1}, {2, 0}, {1, 1}, {2, 0}};
constexpr int PI[4][2]  = {{0, 0}, {0, 1}, {1, 1}, {1, 2}};

__global__ __launch_bounds__(256, 3) void convt_pool_stats(
    const float* __restrict__ x,        // [32][3][32][32][32]
    const float* __restrict__ w,        // [3][16][3][3][3]
    float* __restrict__ pool,           // d_out: [32][16][15][15][15] raw 4^3 sums
    float* __restrict__ partials)       // ws: sums [8192], sumsq [8192], layout [co][n][bd]
{
    const int co  = blockIdx.x;         // 0..15  (innermost: 16 blocks share one x slab)
    const int bd  = blockIdx.y;         // 0..15
    const int n   = blockIdx.z;         // 0..31
    const int tid = threadIdx.x;
    const int bh = tid >> 4;            // 0..15
    const int bw = tid & 15;            // 0..15

    const int id0 = 2 * bd, ih0 = 2 * bh, iw0 = 2 * bw;
    // clamped indices: garbage propagates ONLY into y[..==3] (i_local==2 feeds
    // only lo==3), zeroed below at edge threads before stats/pool.
    const int idc[3] = {id0, id0 + 1, min(id0 + 2, 31)};
    const int ihc[3] = {ih0, ih0 + 1, min(ih0 + 2, 31)};
    const int iw2    = min(iw0 + 2, 31);

    const float* xn = x + (size_t)n * (3 * 32768);

    float y[4][4][4] = {};

    #pragma unroll
    for (int ci = 0; ci < 3; ++ci) {
        const float* xc = xn + ci * 32768;

        // 3x3x3 patch: unconditional float2 + scalar loads (iw0 even -> aligned)
        float xl[3][3][3];
        #pragma unroll
        for (int dd = 0; dd < 3; ++dd) {
            #pragma unroll
            for (int hh = 0; hh < 3; ++hh) {
                const int ro = (idc[dd] * 32 + ihc[hh]) * 32;
                const float2 f2 = *reinterpret_cast<const float2*>(xc + ro + iw0);
                xl[dd][hh][0] = f2.x;
                xl[dd][hh][1] = f2.y;
                xl[dd][hh][2] = xc[ro + iw2];
            }
        }

        // weights: block-uniform address -> scalar loads (SGPRs)
        const float* wp = w + ((size_t)(ci * C_OUT + co)) * 27;
        float wl[27];
        #pragma unroll
        for (int k = 0; k < 27; ++k) wl[k] = wp[k];

        // 216 FMA into 64 independent accumulators, fully static indices
        #pragma unroll
        for (int od = 0; od < 4; ++od) {
            #pragma unroll
            for (int pd = 0; pd < NPAIR[od]; ++pd) {
                const int kd = PK[od][pd], idd = PI[od][pd];
                #pragma unroll
                for (int oh = 0; oh < 4; ++oh) {
                    #pragma unroll
                    for (int ph = 0; ph < NPAIR[oh]; ++ph) {
                        const int kh = PK[oh][ph], ihh = PI[oh][ph];
                        #pragma unroll
                        for (int ow = 0; ow < 4; ++ow) {
                            #pragma unroll
                            for (int pw = 0; pw < NPAIR[ow]; ++pw) {
                                const int kw = PK[ow][pw], iww = PI[ow][pw];
                                y[od][oh][ow] = fmaf(wl[kd * 9 + kh * 3 + kw],
                                                     xl[idd][ihh][iww],
                                                     y[od][oh][ow]);
                            }
                        }
                    }
                }
            }
        }
    }

    // zero invalid (o==63) slices: also kills clamp garbage before stats
    const bool ed = (bd == 15), eh = (bh == 15), ew = (bw == 15);
    if (ed) {
        #pragma unroll
        for (int oh = 0; oh < 4; ++oh)
            #pragma unroll
            for (int ow = 0; ow < 4; ++ow) y[3][oh][ow] = 0.0f;
    }
    if (eh) {
        #pragma unroll
        for (int od = 0; od < 4; ++od)
            #pragma unroll
            for (int ow = 0; ow < 4; ++ow) y[od][3][ow] = 0.0f;
    }
    if (ew) {
        #pragma unroll
        for (int od = 0; od < 4; ++od)
            #pragma unroll
            for (int oh = 0; oh < 4; ++oh) y[od][oh][3] = 0.0f;
    }

    // stats: plain sums, 4 split accumulators for ILP
    float s0 = 0.0f, s1 = 0.0f, q0 = 0.0f, q1 = 0.0f;
    #pragma unroll
    for (int od = 0; od < 4; ++od)
        #pragma unroll
        for (int oh = 0; oh < 4; ++oh)
            #pragma unroll
            for (int ow = 0; ow < 4; ++ow) {
                const float v = y[od][oh][ow];
                if ((ow & 1)) { s1 += v; q1 = fmaf(v, v, q1); }
                else          { s0 += v; q0 = fmaf(v, v, q0); }
            }

    const float ss = s0 + s1;
    // pooled output (interior blocks only; all 64 voxels valid there)
    if (!ed && !eh && !ew) {
        const int oidx = ((((n * C_OUT) + co) * P_OUT + bd) * P_OUT + bh) * P_OUT + bw;
        pool[oidx] = ss;
    }

    // block reduction: wave butterfly + LDS across 4 waves
    float rs = ss, rq = q0 + q1;
    #pragma unroll
    for (int m = 1; m < 64; m <<= 1) {
        rs += __shfl_xor(rs, m, 64);
        rq += __shfl_xor(rq, m, 64);
    }
    __shared__ float red[8];
    const int wave = tid >> 6, lane = tid & 63;
    if (lane == 0) { red[wave] = rs; red[4 + wave] = rq; }
    __syncthreads();
    if (tid == 0) {
        const float ts = red[0] + red[1] + red[2] + red[3];
        const float tq = red[4] + red[5] + red[6] + red[7];
        const int p = (co * N_BATCH + n) * 16 + bd;     // [co][n][bd]
        partials[p] = ts;
        partials[8192 + p] = tq;
    }
}

__global__ __launch_bounds__(256) void finalize_stats(
    const float* __restrict__ partials,  // ws
    const float* __restrict__ gamma,
    const float* __restrict__ beta,
    float* __restrict__ ab)              // ws + 16384: a[16], b[16]
{
    const int c = blockIdx.x;            // 0..15
    const int tid = threadIdx.x;         // 256
    float s = 0.0f, q = 0.0f;
    #pragma unroll
    for (int j = tid; j < 512; j += 256) {
        s += partials[c * 512 + j];
        q += partials[8192 + c * 512 + j];
    }
    #pragma unroll
    for (int m = 1; m < 64; m <<= 1) {
        s += __shfl_xor(s, m, 64);
        q += __shfl_xor(q, m, 64);
    }
    __shared__ float red[8];
    const int wave = tid >> 6, lane = tid & 63;
    if (lane == 0) { red[wave] = s; red[4 + wave] = q; }
    __syncthreads();
    if (tid == 0) {
        const float ts = red[0] + red[1] + red[2] + red[3];
        const float tq = red[4] + red[5] + red[6] + red[7];
        const float mean = ts / COUNT_Y;
        const float var  = tq / COUNT_Y - mean * mean;
        const float invg = rsqrtf(var + 1e-5f) * gamma[c];
        ab[c]      = invg * (1.0f / 64.0f);
        ab[16 + c] = beta[c] - mean * invg;
    }
}

__global__ __launch_bounds__(256) void apply_norm(
    float* __restrict__ out, const float* __restrict__ ab)
{
    const int base = (blockIdx.x * 256 + threadIdx.x) * 4;
    if (base >= TOTAL_OUT) return;
    float4 v = *reinterpret_cast<float4*>(out + base);
    float r[4] = {v.x, v.y, v.z, v.w};
    #pragma unroll
    for (int j = 0; j < 4; ++j) {
        const int c = ((base + j) / POOL3) & 15;
        r[j] = fmaf(r[j], ab[c], ab[16 + c]);
    }
    *reinterpret_cast<float4*>(out + base) = make_float4(r[0], r[1], r[2], r[3]);
}

extern "C" void kernel_launch(void* const* d_in, const int* in_sizes, int n_in,
                              void* d_out, int out_size, void* d_ws, size_t ws_size,
                              hipStream_t stream) {
    const float* x     = (const float*)d_in[0];
    const float* w     = (const float*)d_in[1];
    const float* gamma = (const float*)d_in[2];
    const float* beta  = (const float*)d_in[3];
    float* out = (float*)d_out;
    float* ws  = (float*)d_ws;
    // ws layout (floats): [0,8192) sums, [8192,16384) sumsq, [16384,16416) a,b

    dim3 g1(16, 16, 32);   // co (inner, shares x slab), bd, n
    convt_pool_stats<<<g1, 256, 0, stream>>>(x, w, out, ws);
    finalize_stats<<<16, 256, 0, stream>>>(ws, gamma, beta, ws + 16384);

    const int nv4 = TOTAL_OUT / 4;  // 432,000
    apply_norm<<<(nv4 + 255) / 256, 256, 0, stream>>>(out, ws + 16384);
}